// Round 3
// baseline (96.243 us; speedup 1.0000x reference)
//
#include <hip/hip_runtime.h>
#include <math.h>

#define N_PTS 8192
#define K_CMP 128
#define D_DIM 128
#define KC    16      // k components per block
#define NTB   256     // n rows per block

typedef __attribute__((ext_vector_type(8)))  short  short8;    // 8 x bf16
typedef __attribute__((ext_vector_type(8)))  unsigned short ushort8;
typedef __attribute__((ext_vector_type(4)))  unsigned short ushort4v;
typedef __attribute__((ext_vector_type(4)))  float  f32x4;
typedef __attribute__((ext_vector_type(16))) float  f32x16;

static __device__ __forceinline__ unsigned short f2bf(float f) {
    union { float f; unsigned u; } v; v.f = f;
    unsigned r = v.u + 0x7fffu + ((v.u >> 16) & 1u);   // RNE
    return (unsigned short)(r >> 16);
}
static __device__ __forceinline__ float bf2f(unsigned short h) {
    union { unsigned u; float f; } v; v.u = ((unsigned)h) << 16;
    return v.f;
}

// ---------------- prep: cvec[k] = logdet[k] + log_softmax(weigh)[k] ----------
__global__ void prep_const(const float* __restrict__ logvar,
                           const float* __restrict__ weigh,
                           float* __restrict__ cvec) {
    int k = threadIdx.x;              // 128 threads, 1 block
    float ld = 0.f;
    for (int d = 0; d < D_DIM; ++d) {
        float v = expf(logvar[k * D_DIM + d]);
        ld += logf(fabsf(v) + 1e-8f);
    }
    __shared__ float red[K_CMP];
    float wk = weigh[k];
    red[k] = wk;
    __syncthreads();
    float m = red[0];
    for (int i = 1; i < K_CMP; ++i) m = fmaxf(m, red[i]);
    float s = 0.f;
    for (int i = 0; i < K_CMP; ++i) s += expf(red[i] - m);
    cvec[k] = ld + (wk - m - logf(s));
}

// ---------------- prep: x (fp32) -> xb (bf16) --------------------------------
__global__ void prep_xb(const float* __restrict__ x, unsigned short* __restrict__ xb) {
    int i = blockIdx.x * blockDim.x + threadIdx.x;   // one float4 per thread
    const float4 v = ((const float4*)x)[i];
    ushort4v o;
    o.x = f2bf(v.x); o.y = f2bf(v.y); o.z = f2bf(v.z); o.w = f2bf(v.w);
    *(ushort4v*)&xb[(size_t)i * 4] = o;
}

// ---------------- prep: M'_k = (I + tril(tri,-1)) * diag(var_k), bf16,
// stored XOR-SWIZZLED (16B chunk p at position p ^ (row&7));
// cneg[k][d] = -sum_e M'b[d][e] * mu_k[e]  (fp32) ------------------------------
__global__ void prep_M(const float* __restrict__ tri,
                       const float* __restrict__ logvar,
                       const float* __restrict__ means,
                       unsigned short* __restrict__ Mb,
                       float* __restrict__ cneg) {
    const int k = blockIdx.x;                  // 128 blocks, 256 threads
    __shared__ float var_s[D_DIM], mu_s[D_DIM];
    const int tid = threadIdx.x;
    if (tid < D_DIM) {
        var_s[tid] = expf(logvar[k * D_DIM + tid]);
        mu_s[tid]  = means[k * D_DIM + tid];
    }
    __syncthreads();
    const int wave = tid >> 6, lane = tid & 63;
    const size_t kb = (size_t)k * D_DIM * D_DIM;
    #pragma unroll
    for (int i = 0; i < 8; ++i) {
        const int r = wave * 32 + i * 4 + (lane >> 4);   // row (d)
        const int p = lane & 15;                         // logical 16B chunk
        const int e = p * 8;
        const float4 v0 = *(const float4*)&tri[kb + (size_t)r * D_DIM + e];
        const float4 v1 = *(const float4*)&tri[kb + (size_t)r * D_DIM + e + 4];
        const float vals[8] = {v0.x, v0.y, v0.z, v0.w, v1.x, v1.y, v1.z, v1.w};
        ushort8 ob;
        float cacc = 0.f;
        #pragma unroll
        for (int j = 0; j < 8; ++j) {
            const int ee = e + j;
            float val = (ee < r) ? vals[j] * var_s[ee] : (ee == r ? var_s[r] : 0.f);
            unsigned short b = f2bf(val);
            ((unsigned short*)&ob)[j] = b;
            cacc = fmaf(bf2f(b), mu_s[ee], cacc);
        }
        *(ushort8*)&Mb[kb + (size_t)r * D_DIM + ((p ^ (r & 7)) * 8)] = ob;
        cacc += __shfl_xor(cacc, 1, 64);
        cacc += __shfl_xor(cacc, 2, 64);
        cacc += __shfl_xor(cacc, 4, 64);
        cacc += __shfl_xor(cacc, 8, 64);
        if (p == 0) cneg[k * D_DIM + r] = -cacc;
    }
}

// ---------------- main -------------------------------------------------------
// Block: 8 waves, 256 n-rows x 16 k's, loops k with double-buffered M in LDS.
// Wave (w): d-slab (w&3)*32, n-half (w>>2)*128. X-fragments in registers.
// Z[d][n] = sum_e M'[d][e] X[n][e] - c[d] via MFMA C-operand = -c.
// q[k][n] = sum_d Z^2 accumulated cross-wave with LDS atomics.
__launch_bounds__(512, 2)
__global__ void gmm_main(const unsigned short* __restrict__ xb,
                         const unsigned short* __restrict__ Mb,
                         const float* __restrict__ cneg,
                         const float* __restrict__ cvec,
                         float* __restrict__ logits) {
    __shared__ __align__(16) unsigned short Ms[2][D_DIM][D_DIM];  // 64 KB, swizzled
    __shared__ __align__(16) float cs[KC][D_DIM];                 // 8 KB
    __shared__ __align__(16) float qacc[KC][NTB];                 // 16 KB

    // XCD-aligned decomposition: XCD x (= bid%8) owns k-chunk x for all n-tiles
    const int bid = blockIdx.x;
    const int kc  = bid & 7;
    const int nt  = bid >> 3;        // 0..31
    const int k0  = kc * KC;
    const int t0  = nt * NTB;

    const int tid  = threadIdx.x;
    const int wave = tid >> 6;
    const int lane = tid & 63;
    const int l31  = lane & 31;
    const int lh   = lane >> 5;
    const int dslab = (wave & 3) * 32;
    const int nhalf = (wave >> 2) * 128;
    const int dl    = dslab + l31;       // this lane's M row

    // ---- prologue: cs copy, qacc zero ----
    {
        const float4* cg = (const float4*)(cneg + k0 * D_DIM);
        ((float4*)cs)[tid] = cg[tid];                    // 2048 floats
        const float4 z = {0.f, 0.f, 0.f, 0.f};
        ((float4*)qacc)[tid * 2 + 0] = z;                // 4096 floats
        ((float4*)qacc)[tid * 2 + 1] = z;
    }

    // ---- stage M[k0] into buf 0 (linear DMA; source is pre-swizzled) ----
    #define STAGE(buf, kidx) do {                                              \
        const unsigned short* gsrc_ = Mb + (size_t)(kidx) * (D_DIM * D_DIM);   \
        unsigned short* ldst_ = &Ms[buf][0][0];                                \
        _Pragma("unroll")                                                      \
        for (int i_ = 0; i_ < 4; ++i_) {                                       \
            __builtin_amdgcn_global_load_lds(                                  \
                (const __attribute__((address_space(1))) unsigned int*)       \
                    (gsrc_ + i_ * 4096 + tid * 8),                             \
                (__attribute__((address_space(3))) unsigned int*)             \
                    (ldst_ + i_ * 4096 + tid * 8),                             \
                16, 0, 0);                                                     \
        }                                                                      \
    } while (0)

    STAGE(0, k0);

    // ---- X fragments -> registers (once per block, straight from global) ----
    short8 xf[4][8];
    {
        const unsigned short* xg = xb + (size_t)(t0 + nhalf + l31) * D_DIM + lh * 8;
        #pragma unroll
        for (int nj = 0; nj < 4; ++nj)
            #pragma unroll
            for (int es = 0; es < 8; ++es)
                xf[nj][es] = *(const short8*)&xg[(size_t)(nj * 32) * D_DIM + es * 16];
    }

    asm volatile("s_waitcnt vmcnt(0)");
    __syncthreads();

    int cur = 0;
    #pragma unroll 1
    for (int kk = 0; kk < KC; ++kk) {
        if (kk + 1 < KC) STAGE(cur ^ 1, k0 + kk + 1);

        // cinit = -c fragment in C/D layout: reg r -> row (r&3)+8*(r>>2)+4*lh
        f32x16 cinit;
        #pragma unroll
        for (int j = 0; j < 4; ++j) {
            const f32x4 cj = *(const f32x4*)&cs[kk][dslab + 8 * j + 4 * lh];
            cinit[4 * j + 0] = cj.x; cinit[4 * j + 1] = cj.y;
            cinit[4 * j + 2] = cj.z; cinit[4 * j + 3] = cj.w;
        }

        f32x16 acc0, acc1, acc2, acc3;
        {   // es = 0: C-operand = -c (free acc init)
            const int ch = lh ^ (dl & 7);
            const short8 a = *(const short8*)&Ms[cur][dl][ch * 8];
            acc0 = __builtin_amdgcn_mfma_f32_32x32x16_bf16(a, xf[0][0], cinit, 0, 0, 0);
            acc1 = __builtin_amdgcn_mfma_f32_32x32x16_bf16(a, xf[1][0], cinit, 0, 0, 0);
            acc2 = __builtin_amdgcn_mfma_f32_32x32x16_bf16(a, xf[2][0], cinit, 0, 0, 0);
            acc3 = __builtin_amdgcn_mfma_f32_32x32x16_bf16(a, xf[3][0], cinit, 0, 0, 0);
        }
        #pragma unroll
        for (int es = 1; es < 8; ++es) {
            const int ch = ((es << 1) + lh) ^ (dl & 7);
            const short8 a = *(const short8*)&Ms[cur][dl][ch * 8];
            acc0 = __builtin_amdgcn_mfma_f32_32x32x16_bf16(a, xf[0][es], acc0, 0, 0, 0);
            acc1 = __builtin_amdgcn_mfma_f32_32x32x16_bf16(a, xf[1][es], acc1, 0, 0, 0);
            acc2 = __builtin_amdgcn_mfma_f32_32x32x16_bf16(a, xf[2][es], acc2, 0, 0, 0);
            acc3 = __builtin_amdgcn_mfma_f32_32x32x16_bf16(a, xf[3][es], acc3, 0, 0, 0);
        }

        // q[nj] per col (lane&31): lane-local 16 rows + partner lane (^32)
        float s0 = 0.f, s1 = 0.f, s2 = 0.f, s3 = 0.f;
        #pragma unroll
        for (int r = 0; r < 16; ++r) {
            s0 = fmaf(acc0[r], acc0[r], s0);
            s1 = fmaf(acc1[r], acc1[r], s1);
            s2 = fmaf(acc2[r], acc2[r], s2);
            s3 = fmaf(acc3[r], acc3[r], s3);
        }
        s0 += __shfl_xor(s0, 32, 64);
        s1 += __shfl_xor(s1, 32, 64);
        s2 += __shfl_xor(s2, 32, 64);
        s3 += __shfl_xor(s3, 32, 64);

        const float qa = lh ? s2 : s0;
        const float qb = lh ? s3 : s1;
        atomicAdd(&qacc[kk][nhalf + (lh * 2 + 0) * 32 + l31], qa);
        atomicAdd(&qacc[kk][nhalf + (lh * 2 + 1) * 32 + l31], qb);

        asm volatile("s_waitcnt vmcnt(0)");
        __syncthreads();
        cur ^= 1;
    }

    // ---- epilogue: logits[k][n] = -0.5*q + cvec[k] ----
    {
        const int kk = tid >> 5;            // 0..15
        const int nb = (tid & 31) * 8;      // 0..248
        const float cv = cvec[k0 + kk];
        const f32x4 q0 = *(const f32x4*)&qacc[kk][nb];
        const f32x4 q1 = *(const f32x4*)&qacc[kk][nb + 4];
        f32x4 o0, o1;
        o0.x = -0.5f * q0.x + cv; o0.y = -0.5f * q0.y + cv;
        o0.z = -0.5f * q0.z + cv; o0.w = -0.5f * q0.w + cv;
        o1.x = -0.5f * q1.x + cv; o1.y = -0.5f * q1.y + cv;
        o1.z = -0.5f * q1.z + cv; o1.w = -0.5f * q1.w + cv;
        float* lp = &logits[(size_t)(k0 + kk) * N_PTS + t0 + nb];
        *(f32x4*)lp = o0;
        *(f32x4*)(lp + 4) = o1;
    }
    #undef STAGE
}

// ---------------- lse: out[n] = -(logC + logsumexp_k logits[k][n]) -----------
__global__ void lse_kernel(const float* __restrict__ logits, float* __restrict__ out) {
    const int n = blockIdx.x * blockDim.x + threadIdx.x;
    float m0 = -INFINITY, m1 = -INFINITY, m2 = -INFINITY, m3 = -INFINITY;
    float s0 = 0.f, s1 = 0.f, s2 = 0.f, s3 = 0.f;
    for (int k = 0; k < K_CMP; k += 4) {
        const float v0 = logits[(size_t)(k + 0) * N_PTS + n];
        const float v1 = logits[(size_t)(k + 1) * N_PTS + n];
        const float v2 = logits[(size_t)(k + 2) * N_PTS + n];
        const float v3 = logits[(size_t)(k + 3) * N_PTS + n];
        float nm;
        nm = fmaxf(m0, v0); s0 = s0 * __expf(m0 - nm) + __expf(v0 - nm); m0 = nm;
        nm = fmaxf(m1, v1); s1 = s1 * __expf(m1 - nm) + __expf(v1 - nm); m1 = nm;
        nm = fmaxf(m2, v2); s2 = s2 * __expf(m2 - nm) + __expf(v2 - nm); m2 = nm;
        nm = fmaxf(m3, v3); s3 = s3 * __expf(m3 - nm) + __expf(v3 - nm); m3 = nm;
    }
    const float m = fmaxf(fmaxf(m0, m1), fmaxf(m2, m3));
    const float s = s0 * __expf(m0 - m) + s1 * __expf(m1 - m) +
                    s2 * __expf(m2 - m) + s3 * __expf(m3 - m);
    const float logC = -117.62413225f;   // -0.5 * 128 * log(2*pi)
    out[n] = -(logC + m + logf(s));
}

extern "C" void kernel_launch(void* const* d_in, const int* in_sizes, int n_in,
                              void* d_out, int out_size, void* d_ws, size_t ws_size,
                              hipStream_t stream) {
    const float* x      = (const float*)d_in[0];   // [N, D]
    const float* means  = (const float*)d_in[1];   // [K, D]
    const float* logvar = (const float*)d_in[2];   // [1, K, D]
    const float* tri    = (const float*)d_in[3];   // [1, K, D, D]
    const float* weigh  = (const float*)d_in[4];   // [1, K]
    float* out = (float*)d_out;                    // [N, 1]

    // workspace layout
    unsigned char* ws = (unsigned char*)d_ws;
    unsigned short* Mb   = (unsigned short*)(ws);                              // 4 MB swizzled bf16
    unsigned short* xbuf = (unsigned short*)(ws + (size_t)4 * 1024 * 1024);    // 2 MB bf16
    float*          cneg = (float*)(ws + (size_t)6 * 1024 * 1024);             // 64 KB
    float*          cvec = (float*)(ws + (size_t)6 * 1024 * 1024 + 65536);     // 512 B
    float*          logits = (float*)(ws + (size_t)6 * 1024 * 1024 + 131072);  // 4 MB [K][N]

    hipLaunchKernelGGL(prep_M, dim3(K_CMP), dim3(256), 0, stream,
                       tri, logvar, means, Mb, cneg);
    hipLaunchKernelGGL(prep_xb, dim3((N_PTS * D_DIM / 4) / 256), dim3(256), 0, stream,
                       x, xbuf);
    hipLaunchKernelGGL(prep_const, dim3(1), dim3(128), 0, stream, logvar, weigh, cvec);

    hipLaunchKernelGGL(gmm_main, dim3((K_CMP / KC) * (N_PTS / NTB)), dim3(512), 0, stream,
                       xbuf, Mb, cneg, cvec, logits);

    hipLaunchKernelGGL(lse_kernel, dim3(N_PTS / 128), dim3(128), 0, stream, logits, out);
}

// Round 4
// 57.211 us; speedup vs baseline: 1.6822x; 1.6822x over previous
//
#include <hip/hip_runtime.h>
#include <math.h>

#define N_PTS 8192
#define K_CMP 128
#define D_DIM 128
#define KC    16      // k components per gmm block
#define NTB   128     // n rows per gmm block

typedef __attribute__((ext_vector_type(8)))  short  short8;    // 8 x bf16
typedef __attribute__((ext_vector_type(8)))  unsigned short ushort8;
typedef __attribute__((ext_vector_type(4)))  unsigned short ushort4v;
typedef __attribute__((ext_vector_type(4)))  float  f32x4;
typedef __attribute__((ext_vector_type(16))) float  f32x16;

static __device__ __forceinline__ unsigned short f2bf(float f) {
    union { float f; unsigned u; } v; v.f = f;
    unsigned r = v.u + 0x7fffu + ((v.u >> 16) & 1u);   // RNE
    return (unsigned short)(r >> 16);
}
static __device__ __forceinline__ float bf2f(unsigned short h) {
    union { unsigned u; float f; } v; v.u = ((unsigned)h) << 16;
    return v.f;
}

// ================= prep (fused): blocks 0..127 -> M'/cneg/cvec for k=bid;
//                  blocks 128..255 -> x fp32->bf16 conversion ================
__global__ void prep_all(const float* __restrict__ x,
                         const float* __restrict__ means,
                         const float* __restrict__ logvar,
                         const float* __restrict__ tri,
                         const float* __restrict__ weigh,
                         unsigned short* __restrict__ Mb,
                         unsigned short* __restrict__ xbuf,
                         float* __restrict__ cneg,
                         float* __restrict__ cvec) {
    const int bid = blockIdx.x;
    const int tid = threadIdx.x;

    if (bid >= K_CMP) {
        // x: 1M floats = 262144 float4 over 128 blocks -> 8 float4/thread
        const int base4 = (bid - K_CMP) * 2048 + tid;
        #pragma unroll
        for (int j = 0; j < 8; ++j) {
            const int i4 = base4 + j * 256;
            const float4 v = ((const float4*)x)[i4];
            ushort4v o;
            o.x = f2bf(v.x); o.y = f2bf(v.y); o.z = f2bf(v.z); o.w = f2bf(v.w);
            *(ushort4v*)&xbuf[(size_t)i4 * 4] = o;
        }
        return;
    }

    const int k = bid;
    __shared__ float var_s[D_DIM], mu_s[D_DIM];
    if (tid < D_DIM) {
        var_s[tid] = expf(logvar[k * D_DIM + tid]);
        mu_s[tid]  = means[k * D_DIM + tid];
    }
    __syncthreads();

    const int wave = tid >> 6, lane = tid & 63;

    // wave 0: cvec[k] = logdet + log_softmax(weigh)[k]
    if (wave == 0) {
        float ld = logf(fabsf(var_s[lane]) + 1e-8f) +
                   logf(fabsf(var_s[lane + 64]) + 1e-8f);
        #pragma unroll
        for (int off = 1; off < 64; off <<= 1) ld += __shfl_xor(ld, off, 64);
        const float w1 = weigh[lane], w2 = weigh[lane + 64];
        float mx = fmaxf(w1, w2);
        #pragma unroll
        for (int off = 1; off < 64; off <<= 1) mx = fmaxf(mx, __shfl_xor(mx, off, 64));
        float se = __expf(w1 - mx) + __expf(w2 - mx);
        #pragma unroll
        for (int off = 1; off < 64; off <<= 1) se += __shfl_xor(se, off, 64);
        if (lane == 0) cvec[k] = ld + (weigh[k] - mx - logf(se));
    }

    // all waves: M'_k = (I + tril(tri,-1))*diag(var), bf16, XOR-swizzled chunks;
    // cneg[k][d] = -sum_e M'b[d][e] * mu[e]
    const size_t kb = (size_t)k * D_DIM * D_DIM;
    #pragma unroll
    for (int i = 0; i < 8; ++i) {
        const int r = wave * 32 + i * 4 + (lane >> 4);   // row (d)
        const int p = lane & 15;                         // logical 16B chunk
        const int e = p * 8;
        const float4 v0 = *(const float4*)&tri[kb + (size_t)r * D_DIM + e];
        const float4 v1 = *(const float4*)&tri[kb + (size_t)r * D_DIM + e + 4];
        const float vals[8] = {v0.x, v0.y, v0.z, v0.w, v1.x, v1.y, v1.z, v1.w};
        ushort8 ob;
        float cacc = 0.f;
        #pragma unroll
        for (int j = 0; j < 8; ++j) {
            const int ee = e + j;
            float val = (ee < r) ? vals[j] * var_s[ee] : (ee == r ? var_s[r] : 0.f);
            unsigned short b = f2bf(val);
            ((unsigned short*)&ob)[j] = b;
            cacc = fmaf(bf2f(b), mu_s[ee], cacc);
        }
        *(ushort8*)&Mb[kb + (size_t)r * D_DIM + ((p ^ (r & 7)) * 8)] = ob;
        cacc += __shfl_xor(cacc, 1, 64);
        cacc += __shfl_xor(cacc, 2, 64);
        cacc += __shfl_xor(cacc, 4, 64);
        cacc += __shfl_xor(cacc, 8, 64);
        if (p == 0) cneg[k * D_DIM + r] = -cacc;
    }
}

// ---- per-slab MFMA chain: slab S only needs e < 32*(S+1) (strict-lower M) ----
template<int S>
static __device__ __forceinline__ void slab_mm(
        const unsigned short (*__restrict__ Msc)[D_DIM],
        const float* __restrict__ cb,
        const short8 (&xf)[2][8],
        int l31, int lh,
        f32x16& a0, f32x16& a1) {
    // cinit = -c fragment (C/D layout: reg r -> row (r&3)+8*(r>>2)+4*lh)
    f32x16 ci;
    #pragma unroll
    for (int j = 0; j < 4; ++j) {
        const f32x4 c = *(const f32x4*)&cb[S * 32 + 8 * j + 4 * lh];
        ci[4 * j + 0] = c.x; ci[4 * j + 1] = c.y;
        ci[4 * j + 2] = c.z; ci[4 * j + 3] = c.w;
    }
    const int row = S * 32 + l31;
    {
        const int ch = lh ^ (row & 7);
        const short8 a = *(const short8*)&Msc[row][ch * 8];
        a0 = __builtin_amdgcn_mfma_f32_32x32x16_bf16(a, xf[0][0], ci, 0, 0, 0);
        a1 = __builtin_amdgcn_mfma_f32_32x32x16_bf16(a, xf[1][0], ci, 0, 0, 0);
    }
    #pragma unroll
    for (int es = 1; es < 2 * (S + 1); ++es) {
        const int ch = ((es << 1) + lh) ^ (row & 7);
        const short8 a = *(const short8*)&Msc[row][ch * 8];
        a0 = __builtin_amdgcn_mfma_f32_32x32x16_bf16(a, xf[0][es], a0, 0, 0, 0);
        a1 = __builtin_amdgcn_mfma_f32_32x32x16_bf16(a, xf[1][es], a1, 0, 0, 0);
    }
}

// ================= main ======================================================
// Block: 4 waves, 128 n x 128 d x KC k's, double-buffered M in LDS.
// Wave: slab-pair {p, 3-p} (balanced 10 chunks each) x 64 n.
// Epilogue folds the per-chunk partial logsumexp -> part[kc][n] = (m, s).
__launch_bounds__(256, 2)
__global__ void gmm_main(const unsigned short* __restrict__ xb,
                         const unsigned short* __restrict__ Mb,
                         const float* __restrict__ cneg,
                         const float* __restrict__ cvec,
                         float2* __restrict__ part) {
    __shared__ __align__(16) unsigned short Ms[2][D_DIM][D_DIM];  // 64 KB
    __shared__ __align__(16) float qacc[KC][NTB];                 // 8 KB

    const int bid = blockIdx.x;
    const int kc  = bid & 7;          // XCD-aligned: XCD x owns k-chunk x
    const int nt  = bid >> 3;         // 0..63
    const int k0  = kc * KC;
    const int t0  = nt * NTB;

    const int tid  = threadIdx.x;
    const int wave = tid >> 6;
    const int lane = tid & 63;
    const int l31  = lane & 31;
    const int lh   = lane >> 5;
    const int p    = wave >> 1;       // slab pair {p, 3-p}
    const int nq   = wave & 1;        // 64-row n-half

    // zero qacc (2048 floats)
    {
        const float4 z = {0.f, 0.f, 0.f, 0.f};
        ((float4*)qacc)[tid * 2 + 0] = z;
        ((float4*)qacc)[tid * 2 + 1] = z;
    }

    #define STAGE(buf, kidx) do {                                              \
        const unsigned short* gsrc_ = Mb + (size_t)(kidx) * (D_DIM * D_DIM);   \
        unsigned short* ldst_ = &Ms[buf][0][0];                                \
        _Pragma("unroll")                                                      \
        for (int i_ = 0; i_ < 8; ++i_) {                                       \
            __builtin_amdgcn_global_load_lds(                                  \
                (const __attribute__((address_space(1))) unsigned int*)       \
                    (gsrc_ + i_ * 2048 + tid * 8),                             \
                (__attribute__((address_space(3))) unsigned int*)             \
                    (ldst_ + i_ * 2048 + tid * 8),                             \
                16, 0, 0);                                                     \
        }                                                                      \
    } while (0)

    STAGE(0, k0);

    // X fragments -> registers (64 VGPR, loaded once)
    short8 xf[2][8];
    {
        const unsigned short* xg =
            xb + (size_t)(t0 + nq * 64 + l31) * D_DIM + lh * 8;
        #pragma unroll
        for (int nj = 0; nj < 2; ++nj)
            #pragma unroll
            for (int es = 0; es < 8; ++es)
                xf[nj][es] = *(const short8*)&xg[(size_t)(nj * 32) * D_DIM + es * 16];
    }

    asm volatile("s_waitcnt vmcnt(0)");
    __syncthreads();

    int cur = 0;
    #pragma unroll 1
    for (int kk = 0; kk < KC; ++kk) {
        if (kk + 1 < KC) STAGE(cur ^ 1, k0 + kk + 1);

        const float* cb = cneg + (size_t)(k0 + kk) * D_DIM;
        const unsigned short (*Msc)[D_DIM] = Ms[cur];

        f32x16 acc00, acc01, acc10, acc11;   // [slabA/slabB][nj]
        if (p == 0) {
            slab_mm<0>(Msc, cb, xf, l31, lh, acc00, acc01);
            slab_mm<3>(Msc, cb, xf, l31, lh, acc10, acc11);
        } else {
            slab_mm<1>(Msc, cb, xf, l31, lh, acc00, acc01);
            slab_mm<2>(Msc, cb, xf, l31, lh, acc10, acc11);
        }

        // q partial: sum over this wave's 64 d rows, per col n
        float s0 = 0.f, s1 = 0.f;
        #pragma unroll
        for (int r = 0; r < 16; ++r) {
            s0 = fmaf(acc00[r], acc00[r], s0);
            s0 = fmaf(acc10[r], acc10[r], s0);
            s1 = fmaf(acc01[r], acc01[r], s1);
            s1 = fmaf(acc11[r], acc11[r], s1);
        }
        s0 += __shfl_xor(s0, 32, 64);
        s1 += __shfl_xor(s1, 32, 64);
        const float qv = lh ? s1 : s0;
        atomicAdd(&qacc[kk][nq * 64 + lh * 32 + l31], qv);

        asm volatile("s_waitcnt vmcnt(0)");
        __syncthreads();
        cur ^= 1;
    }
    #undef STAGE

    // epilogue: partial logsumexp over this block's KC components
    if (tid < NTB) {
        float m = -INFINITY, s = 0.f;
        #pragma unroll
        for (int kk = 0; kk < KC; ++kk) {
            const float lg = -0.5f * qacc[kk][tid] + cvec[k0 + kk];
            const float nm = fmaxf(m, lg);
            s = s * __expf(m - nm) + __expf(lg - nm);
            m = nm;
        }
        part[(size_t)kc * N_PTS + t0 + tid] = make_float2(m, s);
    }
}

// ================= final combine: out[n] = -(logC + lse over 8 partials) =====
__global__ void lse2(const float2* __restrict__ part, float* __restrict__ out) {
    const int n = blockIdx.x * 256 + threadIdx.x;
    float2 pr[8];
    float M = -INFINITY;
    #pragma unroll
    for (int j = 0; j < 8; ++j) {
        pr[j] = part[(size_t)j * N_PTS + n];
        M = fmaxf(M, pr[j].x);
    }
    float s = 0.f;
    #pragma unroll
    for (int j = 0; j < 8; ++j)
        s += pr[j].y * __expf(pr[j].x - M);
    const float logC = -117.62413225f;   // -0.5 * 128 * log(2*pi)
    out[n] = -(logC + M + logf(s));
}

extern "C" void kernel_launch(void* const* d_in, const int* in_sizes, int n_in,
                              void* d_out, int out_size, void* d_ws, size_t ws_size,
                              hipStream_t stream) {
    const float* x      = (const float*)d_in[0];   // [N, D]
    const float* means  = (const float*)d_in[1];   // [K, D]
    const float* logvar = (const float*)d_in[2];   // [1, K, D]
    const float* tri    = (const float*)d_in[3];   // [1, K, D, D]
    const float* weigh  = (const float*)d_in[4];   // [1, K]
    float* out = (float*)d_out;                    // [N, 1]

    // workspace layout
    unsigned char* ws = (unsigned char*)d_ws;
    unsigned short* Mb   = (unsigned short*)(ws);                              // 4 MB swizzled bf16
    unsigned short* xbuf = (unsigned short*)(ws + (size_t)4 * 1024 * 1024);    // 2 MB bf16
    float*          cneg = (float*)(ws + (size_t)6 * 1024 * 1024);             // 64 KB
    float*          cvec = (float*)(ws + (size_t)6 * 1024 * 1024 + 65536);     // 512 B
    float2*         part = (float2*)(ws + (size_t)6 * 1024 * 1024 + 131072);   // 512 KB [8][N]

    hipLaunchKernelGGL(prep_all, dim3(256), dim3(256), 0, stream,
                       x, means, logvar, tri, weigh, Mb, xbuf, cneg, cvec);

    hipLaunchKernelGGL(gmm_main, dim3(8 * (N_PTS / NTB)), dim3(256), 0, stream,
                       xbuf, Mb, cneg, cvec, part);

    hipLaunchKernelGGL(lse2, dim3(N_PTS / 256), dim3(256), 0, stream, part, out);
}

// Round 5
// 55.780 us; speedup vs baseline: 1.7254x; 1.0257x over previous
//
#include <hip/hip_runtime.h>
#include <math.h>

#define N_PTS 8192
#define K_CMP 128
#define D_DIM 128
#define KC    16      // k components per gmm block
#define NTB   128     // n rows per gmm block

typedef __attribute__((ext_vector_type(8)))  short  short8;    // 8 x bf16
typedef __attribute__((ext_vector_type(8)))  unsigned short ushort8;
typedef __attribute__((ext_vector_type(4)))  unsigned short ushort4v;
typedef __attribute__((ext_vector_type(4)))  float  f32x4;
typedef __attribute__((ext_vector_type(16))) float  f32x16;

static __device__ __forceinline__ unsigned short f2bf(float f) {
    union { float f; unsigned u; } v; v.f = f;
    unsigned r = v.u + 0x7fffu + ((v.u >> 16) & 1u);   // RNE
    return (unsigned short)(r >> 16);
}
static __device__ __forceinline__ float bf2f(unsigned short h) {
    union { unsigned u; float f; } v; v.u = ((unsigned)h) << 16;
    return v.f;
}

// ================= prep (fused): blocks 0..127 -> M'/cneg/cvec for k=bid;
//                  blocks 128..255 -> x fp32->bf16 conversion ================
__global__ void prep_all(const float* __restrict__ x,
                         const float* __restrict__ means,
                         const float* __restrict__ logvar,
                         const float* __restrict__ tri,
                         const float* __restrict__ weigh,
                         unsigned short* __restrict__ Mb,
                         unsigned short* __restrict__ xbuf,
                         float* __restrict__ cneg,
                         float* __restrict__ cvec) {
    const int bid = blockIdx.x;
    const int tid = threadIdx.x;

    if (bid >= K_CMP) {
        // x: 1M floats = 262144 float4 over 128 blocks -> 8 float4/thread
        const int base4 = (bid - K_CMP) * 2048 + tid;
        #pragma unroll
        for (int j = 0; j < 8; ++j) {
            const int i4 = base4 + j * 256;
            const float4 v = ((const float4*)x)[i4];
            ushort4v o;
            o.x = f2bf(v.x); o.y = f2bf(v.y); o.z = f2bf(v.z); o.w = f2bf(v.w);
            *(ushort4v*)&xbuf[(size_t)i4 * 4] = o;
        }
        return;
    }

    const int k = bid;
    __shared__ float var_s[D_DIM], mu_s[D_DIM];
    if (tid < D_DIM) {
        var_s[tid] = expf(logvar[k * D_DIM + tid]);
        mu_s[tid]  = means[k * D_DIM + tid];
    }
    __syncthreads();

    const int wave = tid >> 6, lane = tid & 63;

    // wave 0: cvec[k] = logdet + log_softmax(weigh)[k]
    if (wave == 0) {
        float ld = logf(fabsf(var_s[lane]) + 1e-8f) +
                   logf(fabsf(var_s[lane + 64]) + 1e-8f);
        #pragma unroll
        for (int off = 1; off < 64; off <<= 1) ld += __shfl_xor(ld, off, 64);
        const float w1 = weigh[lane], w2 = weigh[lane + 64];
        float mx = fmaxf(w1, w2);
        #pragma unroll
        for (int off = 1; off < 64; off <<= 1) mx = fmaxf(mx, __shfl_xor(mx, off, 64));
        float se = __expf(w1 - mx) + __expf(w2 - mx);
        #pragma unroll
        for (int off = 1; off < 64; off <<= 1) se += __shfl_xor(se, off, 64);
        if (lane == 0) cvec[k] = ld + (weigh[k] - mx - logf(se));
    }

    // all waves: M'_k = (I + tril(tri,-1))*diag(var), bf16, XOR-swizzled chunks;
    // cneg[k][d] = -sum_e M'b[d][e] * mu[e]
    const size_t kb = (size_t)k * D_DIM * D_DIM;
    #pragma unroll
    for (int i = 0; i < 8; ++i) {
        const int r = wave * 32 + i * 4 + (lane >> 4);   // row (d)
        const int p = lane & 15;                         // logical 16B chunk
        const int e = p * 8;
        const float4 v0 = *(const float4*)&tri[kb + (size_t)r * D_DIM + e];
        const float4 v1 = *(const float4*)&tri[kb + (size_t)r * D_DIM + e + 4];
        const float vals[8] = {v0.x, v0.y, v0.z, v0.w, v1.x, v1.y, v1.z, v1.w};
        ushort8 ob;
        float cacc = 0.f;
        #pragma unroll
        for (int j = 0; j < 8; ++j) {
            const int ee = e + j;
            float val = (ee < r) ? vals[j] * var_s[ee] : (ee == r ? var_s[r] : 0.f);
            unsigned short b = f2bf(val);
            ((unsigned short*)&ob)[j] = b;
            cacc = fmaf(bf2f(b), mu_s[ee], cacc);
        }
        *(ushort8*)&Mb[kb + (size_t)r * D_DIM + ((p ^ (r & 7)) * 8)] = ob;
        cacc += __shfl_xor(cacc, 1, 64);
        cacc += __shfl_xor(cacc, 2, 64);
        cacc += __shfl_xor(cacc, 4, 64);
        cacc += __shfl_xor(cacc, 8, 64);
        if (p == 0) cneg[k * D_DIM + r] = -cacc;
    }
}

// ---- per-slab MFMA chain: slab S only needs e < 32*(S+1) (strict-lower M) ----
template<int S>
static __device__ __forceinline__ void slab_mm(
        const unsigned short (*__restrict__ Msc)[D_DIM],
        const float* __restrict__ cb,          // LDS row cs[kk]
        const short8 (&xf)[2][8],
        int l31, int lh,
        f32x16& a0, f32x16& a1) {
    // cinit = -c fragment (C/D layout: reg r -> row (r&3)+8*(r>>2)+4*lh)
    f32x16 ci;
    #pragma unroll
    for (int j = 0; j < 4; ++j) {
        const f32x4 c = *(const f32x4*)&cb[S * 32 + 8 * j + 4 * lh];
        ci[4 * j + 0] = c.x; ci[4 * j + 1] = c.y;
        ci[4 * j + 2] = c.z; ci[4 * j + 3] = c.w;
    }
    const int row = S * 32 + l31;
    {
        const int ch = lh ^ (row & 7);
        const short8 a = *(const short8*)&Msc[row][ch * 8];
        a0 = __builtin_amdgcn_mfma_f32_32x32x16_bf16(a, xf[0][0], ci, 0, 0, 0);
        a1 = __builtin_amdgcn_mfma_f32_32x32x16_bf16(a, xf[1][0], ci, 0, 0, 0);
    }
    #pragma unroll
    for (int es = 1; es < 2 * (S + 1); ++es) {
        const int ch = ((es << 1) + lh) ^ (row & 7);
        const short8 a = *(const short8*)&Msc[row][ch * 8];
        a0 = __builtin_amdgcn_mfma_f32_32x32x16_bf16(a, xf[0][es], a0, 0, 0, 0);
        a1 = __builtin_amdgcn_mfma_f32_32x32x16_bf16(a, xf[1][es], a1, 0, 0, 0);
    }
}

// ================= main ======================================================
// Block: 4 waves, 128 n x 128 d x KC k's, double-buffered M in LDS.
// Wave: slab-pair {p, 3-p} (balanced 10 chunks each) x 64 n.
// X fragments pinned in VGPRs via inline-asm loads (not rematerializable).
__attribute__((amdgpu_waves_per_eu(2, 2)))
__launch_bounds__(256, 2)
__global__ void gmm_main(const unsigned short* __restrict__ xb,
                         const unsigned short* __restrict__ Mb,
                         const float* __restrict__ cneg,
                         const float* __restrict__ cvec,
                         float2* __restrict__ part) {
    __shared__ __align__(16) unsigned short Ms[2][D_DIM][D_DIM];  // 64 KB
    __shared__ __align__(16) float cs[KC][D_DIM];                 // 8 KB
    __shared__ __align__(16) float qacc[KC][NTB];                 // 8 KB -> 80 KB total

    const int bid = blockIdx.x;
    const int kc  = bid & 7;          // XCD-aligned: XCD x owns k-chunk x
    const int nt  = bid >> 3;         // 0..63
    const int k0  = kc * KC;
    const int t0  = nt * NTB;

    const int tid  = threadIdx.x;
    const int wave = tid >> 6;
    const int lane = tid & 63;
    const int l31  = lane & 31;
    const int lh   = lane >> 5;
    const int p    = wave >> 1;       // slab pair {p, 3-p}
    const int nq   = wave & 1;        // 64-row n-half

    // zero qacc (2048 floats) + stage cs (2048 floats from cneg)
    {
        const float4 z = {0.f, 0.f, 0.f, 0.f};
        ((float4*)qacc)[tid * 2 + 0] = z;
        ((float4*)qacc)[tid * 2 + 1] = z;
        const float4* cg = (const float4*)(cneg + (size_t)k0 * D_DIM);
        ((float4*)cs)[tid * 2 + 0] = cg[tid * 2 + 0];
        ((float4*)cs)[tid * 2 + 1] = cg[tid * 2 + 1];
    }

    #define STAGE(buf, kidx) do {                                              \
        const unsigned short* gsrc_ = Mb + (size_t)(kidx) * (D_DIM * D_DIM);   \
        unsigned short* ldst_ = &Ms[buf][0][0];                                \
        _Pragma("unroll")                                                      \
        for (int i_ = 0; i_ < 8; ++i_) {                                       \
            __builtin_amdgcn_global_load_lds(                                  \
                (const __attribute__((address_space(1))) unsigned int*)       \
                    (gsrc_ + i_ * 2048 + tid * 8),                             \
                (__attribute__((address_space(3))) unsigned int*)             \
                    (ldst_ + i_ * 2048 + tid * 8),                             \
                16, 0, 0);                                                     \
        }                                                                      \
    } while (0)

    STAGE(0, k0);

    // X fragments -> pinned registers (inline-asm loads: cannot be remat'd)
    short8 xf[2][8];
    {
        const unsigned short* xg0 =
            xb + (size_t)(t0 + nq * 64 + l31) * D_DIM + lh * 8;
        const unsigned short* xg1 = xg0 + (size_t)32 * D_DIM;
        #pragma unroll
        for (int es = 0; es < 8; ++es) {
            asm volatile("global_load_dwordx4 %0, %1, off"
                         : "=v"(xf[0][es]) : "v"(xg0 + es * 16) : "memory");
            asm volatile("global_load_dwordx4 %0, %1, off"
                         : "=v"(xf[1][es]) : "v"(xg1 + es * 16) : "memory");
        }
    }

    asm volatile("s_waitcnt vmcnt(0)" ::: "memory");
    __builtin_amdgcn_sched_barrier(0);     // no MFMA/use may hoist above the wait
    __syncthreads();

    int cur = 0;
    #pragma unroll 1
    for (int kk = 0; kk < KC; ++kk) {
        if (kk + 1 < KC) STAGE(cur ^ 1, k0 + kk + 1);

        const unsigned short (*Msc)[D_DIM] = Ms[cur];

        f32x16 acc00, acc01, acc10, acc11;   // [slabA/slabB][nj]
        if (p == 0) {
            slab_mm<0>(Msc, cs[kk], xf, l31, lh, acc00, acc01);
            slab_mm<3>(Msc, cs[kk], xf, l31, lh, acc10, acc11);
        } else {
            slab_mm<1>(Msc, cs[kk], xf, l31, lh, acc00, acc01);
            slab_mm<2>(Msc, cs[kk], xf, l31, lh, acc10, acc11);
        }

        // q partial: sum over this wave's 64 d rows, per col n (lane&31)
        float s0 = 0.f, s1 = 0.f;
        #pragma unroll
        for (int r = 0; r < 16; ++r) {
            s0 = fmaf(acc00[r], acc00[r], s0);
            s0 = fmaf(acc10[r], acc10[r], s0);
            s1 = fmaf(acc01[r], acc01[r], s1);
            s1 = fmaf(acc11[r], acc11[r], s1);
        }
        s0 += __shfl_xor(s0, 32, 64);
        s1 += __shfl_xor(s1, 32, 64);
        const float qv = lh ? s1 : s0;
        atomicAdd(&qacc[kk][nq * 64 + lh * 32 + l31], qv);

        asm volatile("s_waitcnt vmcnt(0)" ::: "memory");
        __syncthreads();
        cur ^= 1;
    }
    #undef STAGE

    // epilogue: partial logsumexp over this block's KC components
    if (tid < NTB) {
        float m = -INFINITY, s = 0.f;
        #pragma unroll
        for (int kk = 0; kk < KC; ++kk) {
            const float lg = -0.5f * qacc[kk][tid] + cvec[k0 + kk];
            const float nm = fmaxf(m, lg);
            s = s * __expf(m - nm) + __expf(lg - nm);
            m = nm;
        }
        part[(size_t)kc * N_PTS + t0 + tid] = make_float2(m, s);
    }
}

// ================= final combine: out[n] = -(logC + lse over 8 partials) =====
__global__ void lse2(const float2* __restrict__ part, float* __restrict__ out) {
    const int n = blockIdx.x * 256 + threadIdx.x;
    float2 pr[8];
    float M = -INFINITY;
    #pragma unroll
    for (int j = 0; j < 8; ++j) {
        pr[j] = part[(size_t)j * N_PTS + n];
        M = fmaxf(M, pr[j].x);
    }
    float s = 0.f;
    #pragma unroll
    for (int j = 0; j < 8; ++j)
        s += pr[j].y * __expf(pr[j].x - M);
    const float logC = -117.62413225f;   // -0.5 * 128 * log(2*pi)
    out[n] = -(logC + M + logf(s));
}

extern "C" void kernel_launch(void* const* d_in, const int* in_sizes, int n_in,
                              void* d_out, int out_size, void* d_ws, size_t ws_size,
                              hipStream_t stream) {
    const float* x      = (const float*)d_in[0];   // [N, D]
    const float* means  = (const float*)d_in[1];   // [K, D]
    const float* logvar = (const float*)d_in[2];   // [1, K, D]
    const float* tri    = (const float*)d_in[3];   // [1, K, D, D]
    const float* weigh  = (const float*)d_in[4];   // [1, K]
    float* out = (float*)d_out;                    // [N, 1]

    // workspace layout
    unsigned char* ws = (unsigned char*)d_ws;
    unsigned short* Mb   = (unsigned short*)(ws);                              // 4 MB swizzled bf16
    unsigned short* xbuf = (unsigned short*)(ws + (size_t)4 * 1024 * 1024);    // 2 MB bf16
    float*          cneg = (float*)(ws + (size_t)6 * 1024 * 1024);             // 64 KB
    float*          cvec = (float*)(ws + (size_t)6 * 1024 * 1024 + 65536);     // 512 B
    float2*         part = (float2*)(ws + (size_t)6 * 1024 * 1024 + 131072);   // 512 KB [8][N]

    hipLaunchKernelGGL(prep_all, dim3(256), dim3(256), 0, stream,
                       x, means, logvar, tri, weigh, Mb, xbuf, cneg, cvec);

    hipLaunchKernelGGL(gmm_main, dim3(8 * (N_PTS / NTB)), dim3(256), 0, stream,
                       xbuf, Mb, cneg, cvec, part);

    hipLaunchKernelGGL(lse2, dim3(N_PTS / 256), dim3(256), 0, stream, part, out);
}

// Round 6
// 53.557 us; speedup vs baseline: 1.7970x; 1.0415x over previous
//
#include <hip/hip_runtime.h>
#include <math.h>

#define N_PTS 8192
#define K_CMP 128
#define D_DIM 128
#define KC    16      // k components per gmm block
#define NTB   128     // n rows per gmm block

typedef __attribute__((ext_vector_type(8)))  short  short8;    // 8 x bf16
typedef __attribute__((ext_vector_type(8)))  unsigned short ushort8;
typedef __attribute__((ext_vector_type(4)))  unsigned short ushort4v;
typedef __attribute__((ext_vector_type(4)))  float  f32x4;
typedef __attribute__((ext_vector_type(16))) float  f32x16;

static __device__ __forceinline__ unsigned short f2bf(float f) {
    union { float f; unsigned u; } v; v.f = f;
    unsigned r = v.u + 0x7fffu + ((v.u >> 16) & 1u);   // RNE
    return (unsigned short)(r >> 16);
}
static __device__ __forceinline__ float bf2f(unsigned short h) {
    union { unsigned u; float f; } v; v.u = ((unsigned)h) << 16;
    return v.f;
}

// ================= prep (fused): blocks 0..127 -> M'/cneg/cvec for k=bid;
//                  blocks 128..255 -> x fp32->bf16 conversion ================
__global__ void prep_all(const float* __restrict__ x,
                         const float* __restrict__ means,
                         const float* __restrict__ logvar,
                         const float* __restrict__ tri,
                         const float* __restrict__ weigh,
                         unsigned short* __restrict__ Mb,
                         unsigned short* __restrict__ xbuf,
                         float* __restrict__ cneg,
                         float* __restrict__ cvec) {
    const int bid = blockIdx.x;
    const int tid = threadIdx.x;

    if (bid >= K_CMP) {
        // x: 1M floats = 262144 float4 over 128 blocks -> 8 float4/thread
        const int base4 = (bid - K_CMP) * 2048 + tid;
        #pragma unroll
        for (int j = 0; j < 8; ++j) {
            const int i4 = base4 + j * 256;
            const float4 v = ((const float4*)x)[i4];
            ushort4v o;
            o.x = f2bf(v.x); o.y = f2bf(v.y); o.z = f2bf(v.z); o.w = f2bf(v.w);
            *(ushort4v*)&xbuf[(size_t)i4 * 4] = o;
        }
        return;
    }

    const int k = bid;
    __shared__ float var_s[D_DIM], mu_s[D_DIM];
    if (tid < D_DIM) {
        var_s[tid] = expf(logvar[k * D_DIM + tid]);
        mu_s[tid]  = means[k * D_DIM + tid];
    }
    __syncthreads();

    const int wave = tid >> 6, lane = tid & 63;

    // wave 0: cvec[k] = logdet + log_softmax(weigh)[k]
    if (wave == 0) {
        float ld = logf(fabsf(var_s[lane]) + 1e-8f) +
                   logf(fabsf(var_s[lane + 64]) + 1e-8f);
        #pragma unroll
        for (int off = 1; off < 64; off <<= 1) ld += __shfl_xor(ld, off, 64);
        const float w1 = weigh[lane], w2 = weigh[lane + 64];
        float mx = fmaxf(w1, w2);
        #pragma unroll
        for (int off = 1; off < 64; off <<= 1) mx = fmaxf(mx, __shfl_xor(mx, off, 64));
        float se = __expf(w1 - mx) + __expf(w2 - mx);
        #pragma unroll
        for (int off = 1; off < 64; off <<= 1) se += __shfl_xor(se, off, 64);
        if (lane == 0) cvec[k] = ld + (weigh[k] - mx - logf(se));
    }

    // all waves: M'_k = (I + tril(tri,-1))*diag(var), bf16, XOR-swizzled chunks;
    // cneg[k][d] = -sum_e M'b[d][e] * mu[e]
    const size_t kb = (size_t)k * D_DIM * D_DIM;
    #pragma unroll
    for (int i = 0; i < 8; ++i) {
        const int r = wave * 32 + i * 4 + (lane >> 4);   // row (d)
        const int p = lane & 15;                         // logical 16B chunk
        const int e = p * 8;
        const float4 v0 = *(const float4*)&tri[kb + (size_t)r * D_DIM + e];
        const float4 v1 = *(const float4*)&tri[kb + (size_t)r * D_DIM + e + 4];
        const float vals[8] = {v0.x, v0.y, v0.z, v0.w, v1.x, v1.y, v1.z, v1.w};
        ushort8 ob;
        float cacc = 0.f;
        #pragma unroll
        for (int j = 0; j < 8; ++j) {
            const int ee = e + j;
            float val = (ee < r) ? vals[j] * var_s[ee] : (ee == r ? var_s[r] : 0.f);
            unsigned short b = f2bf(val);
            ((unsigned short*)&ob)[j] = b;
            cacc = fmaf(bf2f(b), mu_s[ee], cacc);
        }
        *(ushort8*)&Mb[kb + (size_t)r * D_DIM + ((p ^ (r & 7)) * 8)] = ob;
        cacc += __shfl_xor(cacc, 1, 64);
        cacc += __shfl_xor(cacc, 2, 64);
        cacc += __shfl_xor(cacc, 4, 64);
        cacc += __shfl_xor(cacc, 8, 64);
        if (p == 0) cneg[k * D_DIM + r] = -cacc;
    }
}

// ---- per-slab MFMA chain: slab S only needs e < 32*(S+1) (strict-lower M) ----
template<int S>
static __device__ __forceinline__ void slab_mm(
        const unsigned short (*__restrict__ Msc)[D_DIM],
        const float* __restrict__ cb,          // LDS row cs[kk]
        const short8 (&xf)[2][8],
        int l31, int lh,
        f32x16& a0, f32x16& a1) {
    // cinit = -c fragment (C/D layout: reg r -> row (r&3)+8*(r>>2)+4*lh)
    f32x16 ci;
    #pragma unroll
    for (int j = 0; j < 4; ++j) {
        const f32x4 c = *(const f32x4*)&cb[S * 32 + 8 * j + 4 * lh];
        ci[4 * j + 0] = c.x; ci[4 * j + 1] = c.y;
        ci[4 * j + 2] = c.z; ci[4 * j + 3] = c.w;
    }
    const int row = S * 32 + l31;
    {
        const int ch = lh ^ (row & 7);
        const short8 a = *(const short8*)&Msc[row][ch * 8];
        a0 = __builtin_amdgcn_mfma_f32_32x32x16_bf16(a, xf[0][0], ci, 0, 0, 0);
        a1 = __builtin_amdgcn_mfma_f32_32x32x16_bf16(a, xf[1][0], ci, 0, 0, 0);
    }
    #pragma unroll
    for (int es = 1; es < 2 * (S + 1); ++es) {
        const int ch = ((es << 1) + lh) ^ (row & 7);
        const short8 a = *(const short8*)&Msc[row][ch * 8];
        a0 = __builtin_amdgcn_mfma_f32_32x32x16_bf16(a, xf[0][es], a0, 0, 0, 0);
        a1 = __builtin_amdgcn_mfma_f32_32x32x16_bf16(a, xf[1][es], a1, 0, 0, 0);
    }
}

// ================= main ======================================================
// Block: 4 waves, 128 n x 128 d x KC k's, double-buffered M in LDS.
// T3+T4: counted vmcnt(8) + raw s_barrier (NO vmcnt(0) drain in the loop);
// T5: setprio around the MFMA chains.
__attribute__((amdgpu_waves_per_eu(2, 2)))
__launch_bounds__(256, 2)
__global__ void gmm_main(const unsigned short* __restrict__ xb,
                         const unsigned short* __restrict__ Mb,
                         const float* __restrict__ cneg,
                         const float* __restrict__ cvec,
                         float2* __restrict__ part) {
    __shared__ __align__(16) unsigned short Ms[2][D_DIM][D_DIM];  // 64 KB
    __shared__ __align__(16) float cs[KC][D_DIM];                 // 8 KB
    __shared__ __align__(16) float qacc[KC][NTB];                 // 8 KB -> 80 KB total

    const int bid = blockIdx.x;
    const int kc  = bid & 7;          // XCD-aligned: XCD x owns k-chunk x
    const int nt  = bid >> 3;         // 0..63
    const int k0  = kc * KC;
    const int t0  = nt * NTB;

    const int tid  = threadIdx.x;
    const int wave = tid >> 6;
    const int lane = tid & 63;
    const int l31  = lane & 31;
    const int lh   = lane >> 5;
    const int p    = wave >> 1;       // slab pair {p, 3-p}
    const int nq   = wave & 1;        // 64-row n-half

    // zero qacc (2048 floats) + stage cs (2048 floats from cneg)
    {
        const float4 z = {0.f, 0.f, 0.f, 0.f};
        ((float4*)qacc)[tid * 2 + 0] = z;
        ((float4*)qacc)[tid * 2 + 1] = z;
        const float4* cg = (const float4*)(cneg + (size_t)k0 * D_DIM);
        ((float4*)cs)[tid * 2 + 0] = cg[tid * 2 + 0];
        ((float4*)cs)[tid * 2 + 1] = cg[tid * 2 + 1];
    }

    #define STAGE(buf, kidx) do {                                              \
        const unsigned short* gsrc_ = Mb + (size_t)(kidx) * (D_DIM * D_DIM);   \
        unsigned short* ldst_ = &Ms[buf][0][0];                                \
        _Pragma("unroll")                                                      \
        for (int i_ = 0; i_ < 8; ++i_) {                                       \
            __builtin_amdgcn_global_load_lds(                                  \
                (const __attribute__((address_space(1))) unsigned int*)       \
                    (gsrc_ + i_ * 2048 + tid * 8),                             \
                (__attribute__((address_space(3))) unsigned int*)             \
                    (ldst_ + i_ * 2048 + tid * 8),                             \
                16, 0, 0);                                                     \
        }                                                                      \
    } while (0)

    STAGE(0, k0);

    // X fragments -> pinned registers (inline-asm loads: cannot be remat'd)
    short8 xf[2][8];
    {
        const unsigned short* xg0 =
            xb + (size_t)(t0 + nq * 64 + l31) * D_DIM + lh * 8;
        const unsigned short* xg1 = xg0 + (size_t)32 * D_DIM;
        #pragma unroll
        for (int es = 0; es < 8; ++es) {
            asm volatile("global_load_dwordx4 %0, %1, off"
                         : "=v"(xf[0][es]) : "v"(xg0 + es * 16) : "memory");
            asm volatile("global_load_dwordx4 %0, %1, off"
                         : "=v"(xf[1][es]) : "v"(xg1 + es * 16) : "memory");
        }
    }

    // one-time full drain (X regs + STAGE(0) + cs/qacc LDS writes)
    __syncthreads();

    // per-iteration compute on buffer `c`
    auto COMPUTE = [&](int kk, int c) {
        const unsigned short (*Msc)[D_DIM] = Ms[c];
        f32x16 acc00, acc01, acc10, acc11;   // [slabA/slabB][nj]
        __builtin_amdgcn_s_setprio(1);
        if (p == 0) {
            slab_mm<0>(Msc, cs[kk], xf, l31, lh, acc00, acc01);
            slab_mm<3>(Msc, cs[kk], xf, l31, lh, acc10, acc11);
        } else {
            slab_mm<1>(Msc, cs[kk], xf, l31, lh, acc00, acc01);
            slab_mm<2>(Msc, cs[kk], xf, l31, lh, acc10, acc11);
        }
        __builtin_amdgcn_s_setprio(0);

        // q partial: sum over this wave's 64 d rows, per col n (lane&31)
        float s0 = 0.f, s1 = 0.f;
        #pragma unroll
        for (int r = 0; r < 16; ++r) {
            s0 = fmaf(acc00[r], acc00[r], s0);
            s0 = fmaf(acc10[r], acc10[r], s0);
            s1 = fmaf(acc01[r], acc01[r], s1);
            s1 = fmaf(acc11[r], acc11[r], s1);
        }
        s0 += __shfl_xor(s0, 32, 64);
        s1 += __shfl_xor(s1, 32, 64);
        const float qv = lh ? s1 : s0;
        atomicAdd(&qacc[kk][nq * 64 + lh * 32 + l31], qv);
    };

    int cur = 0;
    #pragma unroll 1
    for (int kk = 0; kk < KC - 1; ++kk) {
        STAGE(cur ^ 1, k0 + kk + 1);                 // prefetch next tile
        asm volatile("s_waitcnt vmcnt(8)" ::: "memory");  // tile kk landed (in-order)
        __builtin_amdgcn_s_barrier();                // all waves' portions landed
        __builtin_amdgcn_sched_barrier(0);
        COMPUTE(kk, cur);
        __builtin_amdgcn_s_barrier();                // reads done before next overwrite
        cur ^= 1;
    }
    // last tile: only its own 8 loads can be outstanding -> full wait
    asm volatile("s_waitcnt vmcnt(0)" ::: "memory");
    __builtin_amdgcn_s_barrier();
    __builtin_amdgcn_sched_barrier(0);
    COMPUTE(KC - 1, cur);
    #undef STAGE

    __syncthreads();   // qacc (ds_add) visibility for epilogue

    // epilogue: partial logsumexp over this block's KC components
    if (tid < NTB) {
        float m = -INFINITY, s = 0.f;
        #pragma unroll
        for (int kk = 0; kk < KC; ++kk) {
            const float lg = -0.5f * qacc[kk][tid] + cvec[k0 + kk];
            const float nm = fmaxf(m, lg);
            s = s * __expf(m - nm) + __expf(lg - nm);
            m = nm;
        }
        part[(size_t)kc * N_PTS + t0 + tid] = make_float2(m, s);
    }
}

// ================= final combine: out[n] = -(logC + lse over 8 partials) =====
__global__ void lse2(const float2* __restrict__ part, float* __restrict__ out) {
    const int n = blockIdx.x * 256 + threadIdx.x;
    float2 pr[8];
    float M = -INFINITY;
    #pragma unroll
    for (int j = 0; j < 8; ++j) {
        pr[j] = part[(size_t)j * N_PTS + n];
        M = fmaxf(M, pr[j].x);
    }
    float s = 0.f;
    #pragma unroll
    for (int j = 0; j < 8; ++j)
        s += pr[j].y * __expf(pr[j].x - M);
    const float logC = -117.62413225f;   // -0.5 * 128 * log(2*pi)
    out[n] = -(logC + M + logf(s));
}

extern "C" void kernel_launch(void* const* d_in, const int* in_sizes, int n_in,
                              void* d_out, int out_size, void* d_ws, size_t ws_size,
                              hipStream_t stream) {
    const float* x      = (const float*)d_in[0];   // [N, D]
    const float* means  = (const float*)d_in[1];   // [K, D]
    const float* logvar = (const float*)d_in[2];   // [1, K, D]
    const float* tri    = (const float*)d_in[3];   // [1, K, D, D]
    const float* weigh  = (const float*)d_in[4];   // [1, K]
    float* out = (float*)d_out;                    // [N, 1]

    // workspace layout
    unsigned char* ws = (unsigned char*)d_ws;
    unsigned short* Mb   = (unsigned short*)(ws);                              // 4 MB swizzled bf16
    unsigned short* xbuf = (unsigned short*)(ws + (size_t)4 * 1024 * 1024);    // 2 MB bf16
    float*          cneg = (float*)(ws + (size_t)6 * 1024 * 1024);             // 64 KB
    float*          cvec = (float*)(ws + (size_t)6 * 1024 * 1024 + 65536);     // 512 B
    float2*         part = (float2*)(ws + (size_t)6 * 1024 * 1024 + 131072);   // 512 KB [8][N]

    hipLaunchKernelGGL(prep_all, dim3(256), dim3(256), 0, stream,
                       x, means, logvar, tri, weigh, Mb, xbuf, cneg, cvec);

    hipLaunchKernelGGL(gmm_main, dim3(8 * (N_PTS / NTB)), dim3(256), 0, stream,
                       xbuf, Mb, cneg, cvec, part);

    hipLaunchKernelGGL(lse2, dim3(N_PTS / 256), dim3(256), 0, stream, part, out);
}